// Round 6
// baseline (105.569 us; speedup 1.0000x reference)
//
#include <hip/hip_runtime.h>

// SigLoss: signature kernel PDE, loss = mean_a( K(X,X) + K(Y,Y) - 2 K(X,Y) ).
// A=256, L=256, D=32.
// R6: TWO pipelined waves per (pair,a) problem, split along columns.
// Wave0 owns columns 0..127, wave1 owns 128..255, running ONE ROW BEHIND.
// Cross-wave data is a single float per row: T0(r) = sum of wave0's c's,
// because K[r+1][128] = 1 + T0(r) in the cumsum form. Wave0's own boundary
// (prev[128] for its lane-63 c) is 1 + its own previous total — no cycle.
// This halves per-lane dY state (64 floats -> resident), halves per-wave
// issue, and doubles waves/SIMD (stall overlap). Scan stays DPP.

#define NROW 255
#define ND 32

#define DPP_ADD(v, ctrl, rmask)                                               \
    ((v) + __int_as_float(__builtin_amdgcn_update_dpp(                        \
               0, __float_as_int(v), (ctrl), (rmask), 0xF, true)))

__global__ __launch_bounds__(128, 1) void sig_pde(const float* __restrict__ X,
                                                  const float* __restrict__ Y,
                                                  float* __restrict__ partial) {
    const int bid = blockIdx.x;
    const int p = bid >> 8;          // 0=xx, 1=yy, 2=xy
    const int a = bid & 255;
    const float* U = (p == 1) ? Y : X;   // rows (i)
    const float* V = (p == 0) ? X : Y;   // cols (j)
    U += (size_t)a * 256 * ND;
    V += (size_t)a * 256 * ND;
    const int tid = threadIdx.x;
    const int wid = tid >> 6;
    const int lane = tid & 63;
    const bool w0 = (wid == 0);

    __shared__ float dxs[NROW * ND];     // 32640 B, dX rows
    __shared__ float t0buf[2];           // T0 ring (wave0 -> wave1)

    // Stage dX = U[i+1]-U[i] into LDS (128 threads)
    const float4* U4 = (const float4*)U;
    float4* dxs4 = (float4*)dxs;
#pragma unroll
    for (int k = 0; k < 16; ++k) {
        int q = tid + (k << 7);          // float4 index
        if (q < 2040) {                  // 2040*4 = 8160 = 255*32
            float4 hi = U4[q + 8];
            float4 lo = U4[q];
            dxs4[q] = make_float4(hi.x - lo.x, hi.y - lo.y, hi.z - lo.z, hi.w - lo.w);
        }
    }

    // Two dY diffs per lane: columns j0, j0+1 (wave0: 0..127, wave1: 128..255)
    const int j0 = (wid << 7) + 2 * lane;
    const float4* V4 = (const float4*)V;
    float dy0[ND], dy1[ND];
    {
        const int r1 = j0 + 1;
        const int r2 = (j0 + 2 < 256) ? j0 + 2 : 255;  // wave1 lane63 -> dy1=0
#pragma unroll
        for (int c = 0; c < 8; ++c) {
            float4 v0 = V4[j0 * 8 + c];
            float4 v1 = V4[r1 * 8 + c];
            float4 v2 = V4[r2 * 8 + c];
            dy0[4 * c + 0] = v1.x - v0.x;  dy1[4 * c + 0] = v2.x - v1.x;
            dy0[4 * c + 1] = v1.y - v0.y;  dy1[4 * c + 1] = v2.y - v1.y;
            dy0[4 * c + 2] = v1.z - v0.z;  dy1[4 * c + 2] = v2.z - v1.z;
            dy0[4 * c + 3] = v1.w - v0.w;  dy1[4 * c + 3] = v2.w - v1.w;
        }
    }
    __syncthreads();

    // K row state: kp0/kp1 = K[r][j0], K[r][j0+1]; row 0 = ones
    float kp0 = 1.0f, kp1 = 1.0f;
    float t0p = 0.0f;  // wave0 lane63: previous row's T0 (row0 boundary = 1+0)

    auto load_row = [&](int i, float (&dst)[ND]) {
        const float4* row4 = (const float4*)(dxs + i * ND);
#pragma unroll
        for (int c = 0; c < 8; ++c) {
            float4 v = row4[c];
            dst[4 * c + 0] = v.x; dst[4 * c + 1] = v.y;
            dst[4 * c + 2] = v.z; dst[4 * c + 3] = v.w;
        }
    };

    auto do_phase = [&](const float (&dxr)[ND], float t0row, int r) {
        // two dots of length 32, 2 chains each (fold the -1 into one chain)
        float i0a = 0.f, i0b = -1.f, i1a = 0.f, i1b = -1.f;
#pragma unroll
        for (int d = 0; d < ND; d += 2) {
            i0a = fmaf(dxr[d], dy0[d], i0a);
            i0b = fmaf(dxr[d + 1], dy0[d + 1], i0b);
            i1a = fmaf(dxr[d], dy1[d], i1a);
            i1b = fmaf(dxr[d + 1], dy1[d + 1], i1b);
        }
        float m0 = i0a + i0b, m1 = i1a + i1b;   // inc - 1

        // kn = next lane's kp0 (wave_shl:1; lane63 -> 0 via bound_ctrl)
        float kn = __int_as_float(__builtin_amdgcn_update_dpp(
            0, __float_as_int(kp0), 0x130 /*wave_shl:1*/, 0xF, 0xF, true));
        float c0 = fmaf(kp0, m0, kp1);
        float c1;
        if (w0) {
            float kne = (lane == 63) ? (1.0f + t0p) : kn;  // prev[128]=1+T0(r-1)
            c1 = fmaf(kp1, m1, kne);
        } else {
            c1 = (lane == 63) ? 0.0f : fmaf(kp1, m1, kn);  // c[255] doesn't exist
        }

        // local pair sum + DPP wave scan
        float L0 = c0;
        float T = c0 + c1;
        float S = T;
        S = DPP_ADD(S, 0x111, 0xF);  // row_shr:1
        S = DPP_ADD(S, 0x112, 0xF);  // row_shr:2
        S = DPP_ADD(S, 0x114, 0xF);  // row_shr:4
        S = DPP_ADD(S, 0x118, 0xF);  // row_shr:8
        S = DPP_ADD(S, 0x142, 0xA);  // row_bcast:15 -> rows 1,3
        S = DPP_ADD(S, 0x143, 0xC);  // row_bcast:31 -> rows 2,3
        float E = S - T;             // exclusive: sum of lower lanes' totals

        if (w0) {
            if (lane == 63) {
                t0buf[r & 1] = S;    // T0(r): total of c[0..127]
                t0p = S;
            }
            kp0 = 1.0f + E;
            kp1 = 1.0f + E + L0;
        } else {
            kp0 = 1.0f + t0row + E;
            kp1 = 1.0f + t0row + E + L0;
        }
    };

    // Pipelined phase loop: wave w processes inc-row r = ph - w.
    // Double-buffered dX row regs, prefetch next row under current dots.
    float bufA[ND], bufB[ND];
    load_row(0, bufA);
    int parity = 0;
    for (int ph = 0; ph < 256; ++ph) {
        const int r = ph - wid;
        if (r >= 0 && r < NROW) {
            float t0row = 0.0f;
            if (!w0) t0row = t0buf[r & 1];   // written by wave0 last phase
            if (parity == 0) {
                if (r + 1 < NROW) load_row(r + 1, bufB);
                do_phase(bufA, t0row, r);
            } else {
                if (r + 1 < NROW) load_row(r + 1, bufA);
                do_phase(bufB, t0row, r);
            }
            parity ^= 1;
        }
        __syncthreads();
    }

    if (!w0 && lane == 63) {
        // kp1 = K[255][255]
        partial[bid] = (p == 2 ? -2.0f : 1.0f) * kp1;
    }
}

__global__ __launch_bounds__(256) void sig_reduce(const float* __restrict__ partial,
                                                  float* __restrict__ out) {
    const int t = threadIdx.x;
    float v = partial[t] + partial[t + 256] + partial[t + 512];
#pragma unroll
    for (int ofs = 32; ofs > 0; ofs >>= 1) v += __shfl_down(v, ofs);
    __shared__ float ws[4];
    if ((t & 63) == 0) ws[t >> 6] = v;
    __syncthreads();
    if (t == 0) out[0] = (ws[0] + ws[1] + ws[2] + ws[3]) * (1.0f / 256.0f);
}

extern "C" void kernel_launch(void* const* d_in, const int* in_sizes, int n_in,
                              void* d_out, int out_size, void* d_ws, size_t ws_size,
                              hipStream_t stream) {
    const float* X = (const float*)d_in[0];
    const float* Y = (const float*)d_in[1];
    float* partial = (float*)d_ws;       // 768 floats
    sig_pde<<<dim3(768), dim3(128), 0, stream>>>(X, Y, partial);
    sig_reduce<<<dim3(1), dim3(256), 0, stream>>>(partial, (float*)d_out);
}

// Round 7
// 80.085 us; speedup vs baseline: 1.3182x; 1.3182x over previous
//
#include <hip/hip_runtime.h>

// SigLoss: signature kernel PDE, loss = mean_a( K(X,X) + K(Y,Y) - 2 K(X,Y) ).
// A=256, L=256, D=32. One 64-lane wave per (pair, a) problem; lane owns
// columns j = 4*lane+s. Row recurrence via cumsum; wave scan via DPP.
// R7 = R3 + amdgpu_waves_per_eu(1,1). Evidence R3/R5/R6 (VGPR=112/112/72):
// the pre-RA scheduler sinks the dY loads into the row loop to hit its
// DEFAULT occupancy target; __launch_bounds__ only sets the MIN waves/EU.
// waves_per_eu(1,1) sets the target itself -> pressure budget ~512 VGPR ->
// dY stays resident. Occupancy is structurally 0.75 waves/SIMD anyway.

#define NROW 255
#define ND 32

// DPP-based add-scan step: v += dpp_move(v). bound_ctrl=1 -> invalid lanes
// contribute 0; row_mask gates which 16-lane rows get written (others add 0).
#define DPP_ADD(v, ctrl, rmask)                                               \
    ((v) + __int_as_float(__builtin_amdgcn_update_dpp(                        \
               0, __float_as_int(v), (ctrl), (rmask), 0xF, true)))

__global__ __launch_bounds__(64)
__attribute__((amdgpu_waves_per_eu(1, 1)))
void sig_pde(const float* __restrict__ X,
             const float* __restrict__ Y,
             float* __restrict__ partial) {
    const int bid = blockIdx.x;
    const int p = bid >> 8;          // 0=xx, 1=yy, 2=xy
    const int a = bid & 255;
    const float* U = (p == 1) ? Y : X;   // rows (i)
    const float* V = (p == 0) ? X : Y;   // cols (j)
    U += (size_t)a * 256 * ND;
    V += (size_t)a * 256 * ND;
    const int lane = threadIdx.x;

    __shared__ float dxs[NROW * ND];     // 32640 B, dX rows

    // Stage dX = U[i+1]-U[i] into LDS
    const float4* U4 = (const float4*)U;
    float4* dxs4 = (float4*)dxs;
#pragma unroll
    for (int k = 0; k < 32; ++k) {
        int q = lane + (k << 6);         // float4 index
        if (q < 2040) {                  // 2040*4 = 8160 = 255*32
            float4 hi = U4[q + 8];
            float4 lo = U4[q];
            dxs4[q] = make_float4(hi.x - lo.x, hi.y - lo.y, hi.z - lo.z, hi.w - lo.w);
        }
    }

    // dY rows j = 4*lane + s into registers (128 VGPR)
    float dy[4][ND];
    const float4* V4 = (const float4*)V;
#pragma unroll
    for (int s = 0; s < 4; ++s) {
        int j = 4 * lane + s;
        if (j < NROW) {
#pragma unroll
            for (int c = 0; c < 8; ++c) {
                float4 hi = V4[(j + 1) * 8 + c];
                float4 lo = V4[j * 8 + c];
                dy[s][4 * c + 0] = hi.x - lo.x;
                dy[s][4 * c + 1] = hi.y - lo.y;
                dy[s][4 * c + 2] = hi.z - lo.z;
                dy[s][4 * c + 3] = hi.w - lo.w;
            }
        } else {                          // only lane 63, s=3 (j=255)
#pragma unroll
            for (int d = 0; d < ND; ++d) dy[s][d] = 0.0f;
        }
    }
    __syncthreads();

    // K row state: kp{0..3} = K[i][4*lane+s], init row 0 = all ones
    float kp0 = 1.0f, kp1 = 1.0f, kp2 = 1.0f, kp3 = 1.0f;

    // Load dX row i from LDS into registers (uniform broadcast, 8x b128)
    auto load_row = [&](int i, float (&dst)[ND]) {
        const float4* row4 = (const float4*)(dxs + i * ND);
#pragma unroll
        for (int c = 0; c < 8; ++c) {
            float4 v = row4[c];
            dst[4 * c + 0] = v.x; dst[4 * c + 1] = v.y;
            dst[4 * c + 2] = v.z; dst[4 * c + 3] = v.w;
        }
    };

    auto do_row = [&](const float (&dxr)[ND]) {
        // inc[s] = dot(dX[i], dY[4*lane+s]) — 8 independent FMA chains
        float ia0 = 0.f, ia1 = 0.f, ia2 = 0.f, ia3 = 0.f;
        float ib0 = 0.f, ib1 = 0.f, ib2 = 0.f, ib3 = 0.f;
#pragma unroll
        for (int d = 0; d < ND; d += 2) {
            ia0 = fmaf(dxr[d], dy[0][d], ia0);
            ib0 = fmaf(dxr[d + 1], dy[0][d + 1], ib0);
            ia1 = fmaf(dxr[d], dy[1][d], ia1);
            ib1 = fmaf(dxr[d + 1], dy[1][d + 1], ib1);
            ia2 = fmaf(dxr[d], dy[2][d], ia2);
            ib2 = fmaf(dxr[d + 1], dy[2][d + 1], ib2);
            ia3 = fmaf(dxr[d], dy[3][d], ia3);
            ib3 = fmaf(dxr[d + 1], dy[3][d + 1], ib3);
        }
        float inc0 = ia0 + ib0, inc1 = ia1 + ib1;
        float inc2 = ia2 + ib2, inc3 = ia3 + ib3;

        // c[j] = K[i][j+1] + K[i][j]*(inc-1); K[i][4l+4] is next lane's kp0.
        // kn via DPP wave_shl:1 (0x130): lane i <- lane i+1, lane 63 -> 0.
        float kn = __int_as_float(__builtin_amdgcn_update_dpp(
            0, __float_as_int(kp0), 0x130 /*wave_shl:1*/, 0xF, 0xF, true));
        float c0 = kp1 + kp0 * (inc0 - 1.0f);
        float c1 = kp2 + kp1 * (inc1 - 1.0f);
        float c2 = kp3 + kp2 * (inc2 - 1.0f);
        float c3 = (lane == 63) ? 0.0f : kn + kp3 * (inc3 - 1.0f);

        // local inclusive sums + DPP wave scan of lane totals
        float L0 = c0, L1 = L0 + c1, L2 = L1 + c2;
        float T = L2 + c3;
        float S = T;
        S = DPP_ADD(S, 0x111, 0xF);  // row_shr:1
        S = DPP_ADD(S, 0x112, 0xF);  // row_shr:2
        S = DPP_ADD(S, 0x114, 0xF);  // row_shr:4
        S = DPP_ADD(S, 0x118, 0xF);  // row_shr:8
        S = DPP_ADD(S, 0x142, 0xA);  // row_bcast:15 -> rows 1,3
        S = DPP_ADD(S, 0x143, 0xC);  // row_bcast:31 -> rows 2,3
        float E = S - T;             // exclusive scan: sum c[0..4*lane-1]
        kp0 = 1.0f + E;
        kp1 = 1.0f + E + L0;
        kp2 = 1.0f + E + L1;
        kp3 = 1.0f + E + L2;
    };

    // Software-pipelined row loop: prefetch row i+1's LDS reads under row i's
    // FMAs (double-buffered registers, all indices compile-time constant).
    float bufA[ND], bufB[ND];
    load_row(0, bufA);
    int i = 0;
    for (; i + 2 <= NROW; i += 2) {
        load_row(i + 1, bufB);
        do_row(bufA);
        if (i + 2 < NROW) load_row(i + 2, bufA);
        do_row(bufB);
    }
    if (i < NROW) do_row(bufA);      // row 254

    if (lane == 63) {
        // kp3 = K[255][255]
        partial[bid] = (p == 2 ? -2.0f : 1.0f) * kp3;
    }
}

__global__ __launch_bounds__(256) void sig_reduce(const float* __restrict__ partial,
                                                  float* __restrict__ out) {
    const int t = threadIdx.x;
    float v = partial[t] + partial[t + 256] + partial[t + 512];
#pragma unroll
    for (int ofs = 32; ofs > 0; ofs >>= 1) v += __shfl_down(v, ofs);
    __shared__ float ws[4];
    if ((t & 63) == 0) ws[t >> 6] = v;
    __syncthreads();
    if (t == 0) out[0] = (ws[0] + ws[1] + ws[2] + ws[3]) * (1.0f / 256.0f);
}

extern "C" void kernel_launch(void* const* d_in, const int* in_sizes, int n_in,
                              void* d_out, int out_size, void* d_ws, size_t ws_size,
                              hipStream_t stream) {
    const float* X = (const float*)d_in[0];
    const float* Y = (const float*)d_in[1];
    float* partial = (float*)d_ws;       // 768 floats
    sig_pde<<<dim3(768), dim3(64), 0, stream>>>(X, Y, partial);
    sig_reduce<<<dim3(1), dim3(256), 0, stream>>>(partial, (float*)d_out);
}

// Round 8
// 79.005 us; speedup vs baseline: 1.3362x; 1.0137x over previous
//
#include <hip/hip_runtime.h>

// SigLoss: signature kernel PDE, loss = mean_a( K(X,X) + K(Y,Y) - 2 K(X,Y) ).
// A=256, L=256, D=32. One 64-lane wave per (pair, a) problem; lane owns
// columns j = 4*lane+s. Row recurrence via cumsum; wave scan via DPP.
// R8: remove the dX diff entirely: inc[r][j] = U[r+1]·dY_j - U[r]·dY_j, so
// keep running G = U[r]·dY_j (4 regs) and dot each RAW U row once. U rows are
// wave-uniform -> s_load_dwordx16 into SGPRs (v_fmac v,s,v costs 0 VGPRs for
// dX). No LDS, no dX row buffers: VGPR demand drops ~220 -> ~155, which the
// allocator will actually grant (R3-R7 evidence: it trims to ~112-132).

#define NROW 255
#define ND 32

#define DPP_ADD(v, ctrl, rmask)                                               \
    ((v) + __int_as_float(__builtin_amdgcn_update_dpp(                        \
               0, __float_as_int(v), (ctrl), (rmask), 0xF, true)))

__global__ __launch_bounds__(64)
__attribute__((amdgpu_waves_per_eu(1, 1)))
void sig_pde(const float* __restrict__ X,
             const float* __restrict__ Y,
             float* __restrict__ partial) {
    const int bid = blockIdx.x;
    const int p = bid >> 8;          // 0=xx, 1=yy, 2=xy
    const int a = bid & 255;
    const float* __restrict__ U = (p == 1) ? Y : X;   // rows (i)
    const float* __restrict__ V = (p == 0) ? X : Y;   // cols (j)
    U += (size_t)a * 256 * ND;
    V += (size_t)a * 256 * ND;
    const int lane = threadIdx.x;

    // dY diffs: 4 columns per lane, target = resident in 128 VGPRs
    float dy[4][ND];
    const float4* V4 = (const float4*)V;
#pragma unroll
    for (int s = 0; s < 4; ++s) {
        int j = 4 * lane + s;
        if (j < NROW) {
#pragma unroll
            for (int c = 0; c < 8; ++c) {
                float4 hi = V4[(j + 1) * 8 + c];
                float4 lo = V4[j * 8 + c];
                dy[s][4 * c + 0] = hi.x - lo.x;
                dy[s][4 * c + 1] = hi.y - lo.y;
                dy[s][4 * c + 2] = hi.z - lo.z;
                dy[s][4 * c + 3] = hi.w - lo.w;
            }
        } else {                          // only lane 63, s=3 (j=255)
#pragma unroll
            for (int d = 0; d < ND; ++d) dy[s][d] = 0.0f;
        }
    }

    // Uniform U row -> SGPRs (s_load_dwordx16): dst is wave-uniform scalar
    float urA[ND], urB[ND];
    auto loadU = [&](int row, float (&dst)[ND]) {
        const float* __restrict__ Ur = U + row * ND;
#pragma unroll
        for (int d = 0; d < ND; ++d) dst[d] = Ur[d];
    };

    // dot(ur, dy[s]) for all 4 s: 8 independent chains, b-chains init at `bi`
    float n0, n1, n2, n3;
    auto dots = [&](const float (&ur)[ND], float bi) {
        float a0 = 0.f, b0 = bi, a1 = 0.f, b1 = bi;
        float a2 = 0.f, b2 = bi, a3 = 0.f, b3 = bi;
#pragma unroll
        for (int d = 0; d < ND; d += 2) {
            a0 = fmaf(ur[d], dy[0][d], a0);
            b0 = fmaf(ur[d + 1], dy[0][d + 1], b0);
            a1 = fmaf(ur[d], dy[1][d], a1);
            b1 = fmaf(ur[d + 1], dy[1][d + 1], b1);
            a2 = fmaf(ur[d], dy[2][d], a2);
            b2 = fmaf(ur[d + 1], dy[2][d + 1], b2);
            a3 = fmaf(ur[d], dy[3][d], a3);
            b3 = fmaf(ur[d + 1], dy[3][d + 1], b3);
        }
        n0 = a0 + b0; n1 = a1 + b1; n2 = a2 + b2; n3 = a3 + b3;
    };

    // gp1[s] = U[r]·dy[s] + 1  (so inc-1 = n - gp1 with n = U[r+1]·dy)
    loadU(0, urA);
    dots(urA, 0.0f);
    float gp10 = n0 + 1.0f, gp11 = n1 + 1.0f, gp12 = n2 + 1.0f, gp13 = n3 + 1.0f;

    // K row state: kp{0..3} = K[r][4*lane+s], row 0 = all ones
    float kp0 = 1.0f, kp1 = 1.0f, kp2 = 1.0f, kp3 = 1.0f;

    auto phase = [&](const float (&ur)[ND]) {   // ur = U row r+1 -> inc row r
        dots(ur, 0.0f);
        float m0 = n0 - gp10, m1 = n1 - gp11;   // inc - 1
        float m2 = n2 - gp12, m3 = n3 - gp13;
        gp10 = n0 + 1.0f; gp11 = n1 + 1.0f;     // off critical path
        gp12 = n2 + 1.0f; gp13 = n3 + 1.0f;

        // c[j] = K[r][j+1] + K[r][j]*(inc-1); K[r][4l+4] = next lane's kp0
        float kn = __int_as_float(__builtin_amdgcn_update_dpp(
            0, __float_as_int(kp0), 0x130 /*wave_shl:1*/, 0xF, 0xF, true));
        float c0 = fmaf(kp0, m0, kp1);
        float c1 = fmaf(kp1, m1, kp2);
        float c2 = fmaf(kp2, m2, kp3);
        float c3 = (lane == 63) ? 0.0f : fmaf(kp3, m3, kn);

        // local inclusive sums + DPP wave scan of lane totals
        float L0 = c0, L1 = L0 + c1, L2 = L1 + c2;
        float T = L2 + c3;
        float S = T;
        S = DPP_ADD(S, 0x111, 0xF);  // row_shr:1
        S = DPP_ADD(S, 0x112, 0xF);  // row_shr:2
        S = DPP_ADD(S, 0x114, 0xF);  // row_shr:4
        S = DPP_ADD(S, 0x118, 0xF);  // row_shr:8
        S = DPP_ADD(S, 0x142, 0xA);  // row_bcast:15 -> rows 1,3
        S = DPP_ADD(S, 0x143, 0xC);  // row_bcast:31 -> rows 2,3
        float E = S - T;             // exclusive scan: sum c[0..4*lane-1]
        kp0 = 1.0f + E;
        kp1 = 1.0f + E + L0;
        kp2 = 1.0f + E + L1;
        kp3 = 1.0f + E + L2;
    };

    // Pipelined row loop: SGPR double-buffer, prefetch next U row under dots.
    loadU(1, urA);                    // U row 1 -> inc row 0
    int r = 0;
    for (; r + 1 < NROW; r += 2) {    // r = 0,2,...,252
        loadU(r + 2, urB);
        phase(urA);                   // inc row r
        loadU(r + 3, urA);            // r+3 <= 255 for r <= 252
        phase(urB);                   // inc row r+1
    }
    phase(urA);                       // inc row 254 (U row 255)

    if (lane == 63) {
        // kp3 = K[255][255]
        partial[bid] = (p == 2 ? -2.0f : 1.0f) * kp3;
    }
}

__global__ __launch_bounds__(256) void sig_reduce(const float* __restrict__ partial,
                                                  float* __restrict__ out) {
    const int t = threadIdx.x;
    float v = partial[t] + partial[t + 256] + partial[t + 512];
#pragma unroll
    for (int ofs = 32; ofs > 0; ofs >>= 1) v += __shfl_down(v, ofs);
    __shared__ float ws[4];
    if ((t & 63) == 0) ws[t >> 6] = v;
    __syncthreads();
    if (t == 0) out[0] = (ws[0] + ws[1] + ws[2] + ws[3]) * (1.0f / 256.0f);
}

extern "C" void kernel_launch(void* const* d_in, const int* in_sizes, int n_in,
                              void* d_out, int out_size, void* d_ws, size_t ws_size,
                              hipStream_t stream) {
    const float* X = (const float*)d_in[0];
    const float* Y = (const float*)d_in[1];
    float* partial = (float*)d_ws;       // 768 floats
    sig_pde<<<dim3(768), dim3(64), 0, stream>>>(X, Y, partial);
    sig_reduce<<<dim3(1), dim3(256), 0, stream>>>(partial, (float*)d_out);
}